// Round 1
// baseline (273.941 us; speedup 1.0000x reference)
//
#include <hip/hip_runtime.h>

#define EDIM 300
#define NB   128
#define NQ   16
#define ND   1024
#define NK   11
#define BLOCK 128
#define MDOC  4
#define TDOCS 256                 // docs per block
#define BLOCKS_PER_B 4            // 1024 / 256
#define NPANEL 10                 // 9 full 32-float panels + one 12-float remainder
#define PPITCH 36                 // panel row pitch in floats (32 + 4 pad)
#define SIMP 260                  // sim_t row pitch (256 + 4 pad)

// ---------------- Kernel 1: fused qnorm + staged sim + RBF partials ----------------
// R9 change: register-prefetch double-buffer of the panel gather (T14 async-STAGE
// split). Panel p+1's 16x global_load_dwordx4 are ISSUED into a 64-VGPR buffer
// before compute(p) starts; after the compute-done barrier the regs are dumped to
// the (single) LDS panel buffer. Compute per panel (~2300 cyc VALU) now covers the
// ~900-cyc random-row gather latency that previously stalled every panel behind a
// barrier (R8 profile: VALUBusy 32%, 1 wave/SIMD, HBM 16% peak -> latency-bound).
__global__ __launch_bounds__(BLOCK) void knrm_main(
    const int*   __restrict__ dtoks,
    const int*   __restrict__ qtoks,
    const float* __restrict__ emb,
    const float* __restrict__ mus,
    const float* __restrict__ sigmas,
    float*       __restrict__ part) {
    __shared__ __align__(16) float qn_s[NQ * EDIM];      // 19.2 KB
    __shared__ __align__(16) float panel[TDOCS * PPITCH];// 36.9 KB
    __shared__ int   dtok_s[TDOCS];                      // 1 KB
    __shared__ float rs_s[NQ];
    __shared__ __align__(16) float sim_t[NQ * SIMP];     // 16.6 KB
    __shared__ float red_s[NK * NQ * 8];                 // 5.6 KB
    // total ~77.6 KB -> 2 blocks/CU

    const int blk   = blockIdx.x;
    const int b     = blk >> 2;
    const int dbase = (blk & 3) * TDOCS;
    const int tid   = threadIdx.x;
    const int lane  = tid & 63;
    const int w     = tid >> 6;          // q-half (wave-uniform)

    // ---- doc-token tile + raw q rows (coalesced, float4-vectorized) ----
    for (int i = tid; i < TDOCS; i += BLOCK) dtok_s[i] = dtoks[b * ND + dbase + i];
    for (int i = tid; i < NQ * (EDIM / 4); i += BLOCK) {   // 1200 float4s; 300%4==0
        int q = i / (EDIM / 4), e4 = i - q * (EDIM / 4);
        ((float4*)qn_s)[i] =
            *(const float4*)(emb + (size_t)qtoks[b * NQ + q] * EDIM + e4 * 4);
    }
    __syncthreads();                     // dtok_s + raw qn_s visible

    const int s  = tid & 7;              // 128B slice index within a panel row
    const int r0 = tid >> 3;             // 0..15
    float4 pf[16];                       // prefetch buffer: 64 VGPRs

    auto pf_load = [&](int p) {          // issue panel-p gathers into regs
        if (p < 9 || s < 3) {            // remainder panel: 12 floats = 3 slices
#pragma unroll
            for (int j = 0; j < 16; ++j) {
                const float* src =
                    emb + (size_t)dtok_s[r0 + 16 * j] * EDIM + p * 32 + s * 4;
                pf[j] = *(const float4*)src;
            }
        }
    };
    auto pf_write = [&](int p) {         // drain regs -> LDS (vmcnt wait lands here)
        if (p < 9 || s < 3) {
#pragma unroll
            for (int j = 0; j < 16; ++j)
                *(float4*)&panel[(r0 + 16 * j) * PPITCH + s * 4] = pf[j];
        }
    };

    pf_load(0);                          // hide panel-0 gather under q-norm phase
    {   // q norms
        int q = tid >> 3, j = tid & 7;
        float ss = 0.f;
        for (int e = j; e < EDIM; e += 8) { float v = qn_s[q * EDIM + e]; ss += v * v; }
        ss += __shfl_xor(ss, 1, 64);
        ss += __shfl_xor(ss, 2, 64);
        ss += __shfl_xor(ss, 4, 64);
        if (j == 0) rs_s[q] = 1.0f / (sqrtf(ss) + 1e-9f);
    }
    __syncthreads();
    for (int i = tid; i < NQ * (EDIM / 4); i += BLOCK) {
        float4 v = ((float4*)qn_s)[i];
        float r = rs_s[i / (EDIM / 4)];
        v.x *= r; v.y *= r; v.z *= r; v.w *= r;
        ((float4*)qn_s)[i] = v;
    }
    pf_write(0);                         // panel 0 -> LDS
    pf_load(1);                          // panel 1 in flight across compute(0)
    __syncthreads();                     // panel 0 + scaled qn_s visible

    float sims[MDOC][8];
#pragma unroll
    for (int m = 0; m < MDOC; ++m)
#pragma unroll
        for (int qq = 0; qq < 8; ++qq) sims[m][qq] = 0.f;
    float ssq[MDOC] = {0.f, 0.f, 0.f, 0.f};

    for (int p = 0; p < NPANEL; ++p) {
        // ---- compute on panel p (loads for p+1 already in flight) ----
        const int cmax = (p == 9) ? 3 : 8;
        for (int cc = 0; cc < cmax; ++cc) {
            float4 dv[MDOC];
#pragma unroll
            for (int m = 0; m < MDOC; ++m)
                dv[m] = *(const float4*)&panel[(lane + 64 * m) * PPITCH + cc * 4];
#pragma unroll
            for (int m = 0; m < MDOC; ++m)
                ssq[m] += dv[m].x*dv[m].x + dv[m].y*dv[m].y + dv[m].z*dv[m].z + dv[m].w*dv[m].w;
            const float* qb = qn_s + (size_t)w * 8 * EDIM + (p * 8 + cc) * 4;
#pragma unroll
            for (int qq = 0; qq < 8; ++qq) {
                float4 qv = *(const float4*)(qb + qq * EDIM);   // LDS broadcast
#pragma unroll
                for (int m = 0; m < MDOC; ++m) {
                    sims[m][qq] += qv.x*dv[m].x + qv.y*dv[m].y + qv.z*dv[m].z + qv.w*dv[m].w;
                }
            }
        }
        __syncthreads();                 // panel p fully consumed
        if (p < 9) {
            pf_write(p + 1);             // drain in-flight loads -> LDS
            if (p < 8) pf_load(p + 2);   // issue next gather before compute(p+1)
            __syncthreads();             // panel p+1 ready
        }
    }

    // ---- normalize + write sim_t (pad docs: tok0 -> zero row -> sim 0) ----
#pragma unroll
    for (int m = 0; m < MDOC; ++m) {
        float rn = 1.0f / (sqrtf(ssq[m]) + 1e-9f);
#pragma unroll
        for (int qq = 0; qq < 8; ++qq)
            sim_t[(w * 8 + qq) * SIMP + lane + 64 * m] = sims[m][qq] * rn;
    }
    __syncthreads();

    // ---- RBF bank: thread = (q = tid&15, slice sl of 8 x 32 docs) ----
    {
        const int q = tid & 15;
        const int sl = tid >> 4;
        float mu[NK], cc2[NK], acc[NK];
#pragma unroll
        for (int k = 0; k < NK; ++k) {
            mu[k] = mus[k];
            float sg = sigmas[k];
            cc2[k] = -0.5f / (sg * sg);
            acc[k] = 0.f;
        }
        const float* row = sim_t + q * SIMP + sl * 32;
#pragma unroll
        for (int i = 0; i < 8; ++i) {
            float4 s4 = *(const float4*)(row + i * 4);
#pragma unroll
            for (int k = 0; k < NK; ++k) {
                float e0 = s4.x - mu[k], e1 = s4.y - mu[k];
                float e2 = s4.z - mu[k], e3 = s4.w - mu[k];
                acc[k] += __expf(cc2[k]*e0*e0) + __expf(cc2[k]*e1*e1)
                        + __expf(cc2[k]*e2*e2) + __expf(cc2[k]*e3*e3);
            }
        }
#pragma unroll
        for (int k = 0; k < NK; ++k) red_s[(k * NQ + q) * 8 + sl] = acc[k];
    }
    __syncthreads();

    // NK*NQ = 176 > BLOCK = 128: stride the write (R3 bug class).
    for (int t = tid; t < NK * NQ; t += BLOCK) {
        float r = 0.f;
#pragma unroll
        for (int j = 0; j < 8; ++j) r += red_s[t * 8 + j];
        part[blk * (NK * NQ) + t] = r;
    }
}

// ---------------- Kernel 2: sum partials, masked log-sum over q, FC ----------------
__global__ void knrm_final(const float* __restrict__ part,
                           const int*   __restrict__ qtoks,
                           const float* __restrict__ fc_w,
                           const float* __restrict__ fc_b,
                           float*       __restrict__ out) {
    __shared__ float red[NK * NQ];
    __shared__ float ks[NK];
    int b = blockIdx.x;
    int t = threadIdx.x;
    if (t < NK * NQ) {
        int q = t & 15;
        float r = 0.f;
        for (int j = 0; j < BLOCKS_PER_B; ++j)
            r += part[(b * BLOCKS_PER_B + j) * (NK * NQ) + t];
        red[t] = (qtoks[b * NQ + q] != 0) ? logf(r + 1e-6f) : 0.f;
    }
    __syncthreads();
    if (t < NK) {
        float s = 0.f;
        for (int q = 0; q < NQ; ++q) s += red[t * NQ + q];
        ks[t] = s * fc_w[t];
    }
    __syncthreads();
    if (t == 0) {
        float s = fc_b[0];
        for (int k = 0; k < NK; ++k) s += ks[k];
        out[b] = s;
    }
}

extern "C" void kernel_launch(void* const* d_in, const int* in_sizes, int n_in,
                              void* d_out, int out_size, void* d_ws, size_t ws_size,
                              hipStream_t stream) {
    const int*   doctoks   = (const int*)  d_in[0];   // [128,1024]
    const int*   querytoks = (const int*)  d_in[1];   // [128,16]
    // d_in[2] = query_idf: unused by the reference
    const float* emb       = (const float*)d_in[3];   // [100000,300]
    const float* mus       = (const float*)d_in[4];   // [11]
    const float* sigmas    = (const float*)d_in[5];   // [11]
    const float* fc_w      = (const float*)d_in[6];   // [1,11]
    const float* fc_b      = (const float*)d_in[7];   // [1]
    float* out = (float*)d_out;                        // [128]

    float* part = (float*)d_ws;                        // [512][176] floats

    knrm_main<<<NB * BLOCKS_PER_B, BLOCK, 0, stream>>>(doctoks, querytoks, emb,
                                                       mus, sigmas, part);
    knrm_final<<<NB, 192, 0, stream>>>(part, querytoks, fc_w, fc_b, out);
}

// Round 2
// 213.493 us; speedup vs baseline: 1.2831x; 1.2831x over previous
//
#include <hip/hip_runtime.h>

#define EDIM 300
#define NB   128
#define NQ   16
#define ND   1024
#define NK   11
#define BLOCK 128
#define MDOC  4
#define TDOCS 256                 // docs per block
#define BLOCKS_PER_B 4            // 1024 / 256
#define NPANEL 10                 // 9 full 32-float panels + one 12-float remainder
#define PPITCH 36                 // panel row pitch in floats (32 + 4 pad)
#define SIMP 260                  // sim_t row pitch (256 + 4 pad)

// R10: R9's register-prefetch double-buffer, with the scratch bug fixed.
// R9 post-mortem: pf[16] array + lambdas went to SCRATCH (WRITE_SIZE 352KB ->
// 164MB == 65536 thr x 256B x 10 panels; VGPR_Count stuck at 132) -> 77->130us.
// Fix: 16 NAMED float4 registers + macro unroll (no array indexing at all),
// 16 hoisted row-base pointers (saves per-panel addr VALU), and
// __launch_bounds__(128,1) to unlock the 256-VGPR budget (we are LDS-bound at
// 2 blocks/CU = 1 wave/SIMD regardless, so VGPR growth is free).

#define PF_L(j)  pf##j = *(const float4*)(rp##j + pp * 32)
#define PF_LOAD(p) do { const int pp = (p); if (pp < 9 || s < 3) { \
    PF_L(0);  PF_L(1);  PF_L(2);  PF_L(3);  PF_L(4);  PF_L(5);  PF_L(6);  PF_L(7); \
    PF_L(8);  PF_L(9);  PF_L(10); PF_L(11); PF_L(12); PF_L(13); PF_L(14); PF_L(15); } } while (0)

#define PF_S(j)  *(float4*)&panel[(r0 + 16 * (j)) * PPITCH + s * 4] = pf##j
#define PF_WRITE(p) do { if ((p) < 9 || s < 3) { \
    PF_S(0);  PF_S(1);  PF_S(2);  PF_S(3);  PF_S(4);  PF_S(5);  PF_S(6);  PF_S(7); \
    PF_S(8);  PF_S(9);  PF_S(10); PF_S(11); PF_S(12); PF_S(13); PF_S(14); PF_S(15); } } while (0)

__global__ __launch_bounds__(BLOCK, 1) void knrm_main(
    const int*   __restrict__ dtoks,
    const int*   __restrict__ qtoks,
    const float* __restrict__ emb,
    const float* __restrict__ mus,
    const float* __restrict__ sigmas,
    float*       __restrict__ part) {
    __shared__ __align__(16) float qn_s[NQ * EDIM];      // 19.2 KB
    __shared__ __align__(16) float panel[TDOCS * PPITCH];// 36.9 KB
    __shared__ int   dtok_s[TDOCS];                      // 1 KB
    __shared__ float rs_s[NQ];
    __shared__ __align__(16) float sim_t[NQ * SIMP];     // 16.6 KB
    __shared__ float red_s[NK * NQ * 8];                 // 5.6 KB
    // total ~77.6 KB -> 2 blocks/CU

    const int blk   = blockIdx.x;
    const int b     = blk >> 2;
    const int dbase = (blk & 3) * TDOCS;
    const int tid   = threadIdx.x;
    const int lane  = tid & 63;
    const int w     = tid >> 6;          // q-half (wave-uniform)

    // ---- doc-token tile + raw q rows (coalesced, float4-vectorized) ----
    for (int i = tid; i < TDOCS; i += BLOCK) dtok_s[i] = dtoks[b * ND + dbase + i];
    for (int i = tid; i < NQ * (EDIM / 4); i += BLOCK) {   // 300%4==0
        int q = i / (EDIM / 4), e4 = i - q * (EDIM / 4);
        ((float4*)qn_s)[i] =
            *(const float4*)(emb + (size_t)qtoks[b * NQ + q] * EDIM + e4 * 4);
    }
    __syncthreads();                     // dtok_s + raw qn_s visible

    const int s  = tid & 7;              // 128B slice index within a panel row
    const int r0 = tid >> 3;             // 0..15

    // hoisted per-thread row base pointers (rows fixed across panels)
    const float* rp0  = emb + (size_t)dtok_s[r0 +   0] * EDIM + s * 4;
    const float* rp1  = emb + (size_t)dtok_s[r0 +  16] * EDIM + s * 4;
    const float* rp2  = emb + (size_t)dtok_s[r0 +  32] * EDIM + s * 4;
    const float* rp3  = emb + (size_t)dtok_s[r0 +  48] * EDIM + s * 4;
    const float* rp4  = emb + (size_t)dtok_s[r0 +  64] * EDIM + s * 4;
    const float* rp5  = emb + (size_t)dtok_s[r0 +  80] * EDIM + s * 4;
    const float* rp6  = emb + (size_t)dtok_s[r0 +  96] * EDIM + s * 4;
    const float* rp7  = emb + (size_t)dtok_s[r0 + 112] * EDIM + s * 4;
    const float* rp8  = emb + (size_t)dtok_s[r0 + 128] * EDIM + s * 4;
    const float* rp9  = emb + (size_t)dtok_s[r0 + 144] * EDIM + s * 4;
    const float* rp10 = emb + (size_t)dtok_s[r0 + 160] * EDIM + s * 4;
    const float* rp11 = emb + (size_t)dtok_s[r0 + 176] * EDIM + s * 4;
    const float* rp12 = emb + (size_t)dtok_s[r0 + 192] * EDIM + s * 4;
    const float* rp13 = emb + (size_t)dtok_s[r0 + 208] * EDIM + s * 4;
    const float* rp14 = emb + (size_t)dtok_s[r0 + 224] * EDIM + s * 4;
    const float* rp15 = emb + (size_t)dtok_s[r0 + 240] * EDIM + s * 4;

    float4 pf0, pf1, pf2, pf3, pf4, pf5, pf6, pf7,
           pf8, pf9, pf10, pf11, pf12, pf13, pf14, pf15;   // 64 named VGPRs

    PF_LOAD(0);                          // hide panel-0 gather under q-norm phase
    {   // q norms
        int q = tid >> 3, j = tid & 7;
        float ss = 0.f;
        for (int e = j; e < EDIM; e += 8) { float v = qn_s[q * EDIM + e]; ss += v * v; }
        ss += __shfl_xor(ss, 1, 64);
        ss += __shfl_xor(ss, 2, 64);
        ss += __shfl_xor(ss, 4, 64);
        if (j == 0) rs_s[q] = 1.0f / (sqrtf(ss) + 1e-9f);
    }
    __syncthreads();
    for (int i = tid; i < NQ * (EDIM / 4); i += BLOCK) {
        float4 v = ((float4*)qn_s)[i];
        float r = rs_s[i / (EDIM / 4)];
        v.x *= r; v.y *= r; v.z *= r; v.w *= r;
        ((float4*)qn_s)[i] = v;
    }
    PF_WRITE(0);                         // panel 0 -> LDS
    PF_LOAD(1);                          // panel 1 in flight across compute(0)
    __syncthreads();                     // panel 0 + scaled qn_s visible

    float sims[MDOC][8];
#pragma unroll
    for (int m = 0; m < MDOC; ++m)
#pragma unroll
        for (int qq = 0; qq < 8; ++qq) sims[m][qq] = 0.f;
    float ssq[MDOC] = {0.f, 0.f, 0.f, 0.f};

    for (int p = 0; p < NPANEL; ++p) {
        // ---- compute on panel p (loads for p+1 already in flight) ----
        const int cmax = (p == 9) ? 3 : 8;
        for (int cc = 0; cc < cmax; ++cc) {
            float4 dv[MDOC];
#pragma unroll
            for (int m = 0; m < MDOC; ++m)
                dv[m] = *(const float4*)&panel[(lane + 64 * m) * PPITCH + cc * 4];
#pragma unroll
            for (int m = 0; m < MDOC; ++m)
                ssq[m] += dv[m].x*dv[m].x + dv[m].y*dv[m].y + dv[m].z*dv[m].z + dv[m].w*dv[m].w;
            const float* qb = qn_s + (size_t)w * 8 * EDIM + (p * 8 + cc) * 4;
#pragma unroll
            for (int qq = 0; qq < 8; ++qq) {
                float4 qv = *(const float4*)(qb + qq * EDIM);   // LDS broadcast
#pragma unroll
                for (int m = 0; m < MDOC; ++m) {
                    sims[m][qq] += qv.x*dv[m].x + qv.y*dv[m].y + qv.z*dv[m].z + qv.w*dv[m].w;
                }
            }
        }
        __syncthreads();                 // panel p fully consumed
        if (p < 9) {
            PF_WRITE(p + 1);             // drain in-flight loads -> LDS
            if (p < 8) PF_LOAD(p + 2);   // issue next gather before compute(p+1)
            __syncthreads();             // panel p+1 ready
        }
    }

    // ---- normalize + write sim_t (pad docs: tok0 -> zero row -> sim 0) ----
#pragma unroll
    for (int m = 0; m < MDOC; ++m) {
        float rn = 1.0f / (sqrtf(ssq[m]) + 1e-9f);
#pragma unroll
        for (int qq = 0; qq < 8; ++qq)
            sim_t[(w * 8 + qq) * SIMP + lane + 64 * m] = sims[m][qq] * rn;
    }
    __syncthreads();

    // ---- RBF bank: thread = (q = tid&15, slice sl of 8 x 32 docs) ----
    {
        const int q = tid & 15;
        const int sl = tid >> 4;
        float mu[NK], cc2[NK], acc[NK];
#pragma unroll
        for (int k = 0; k < NK; ++k) {
            mu[k] = mus[k];
            float sg = sigmas[k];
            cc2[k] = -0.5f / (sg * sg);
            acc[k] = 0.f;
        }
        const float* row = sim_t + q * SIMP + sl * 32;
#pragma unroll
        for (int i = 0; i < 8; ++i) {
            float4 s4 = *(const float4*)(row + i * 4);
#pragma unroll
            for (int k = 0; k < NK; ++k) {
                float e0 = s4.x - mu[k], e1 = s4.y - mu[k];
                float e2 = s4.z - mu[k], e3 = s4.w - mu[k];
                acc[k] += __expf(cc2[k]*e0*e0) + __expf(cc2[k]*e1*e1)
                        + __expf(cc2[k]*e2*e2) + __expf(cc2[k]*e3*e3);
            }
        }
#pragma unroll
        for (int k = 0; k < NK; ++k) red_s[(k * NQ + q) * 8 + sl] = acc[k];
    }
    __syncthreads();

    // NK*NQ = 176 > BLOCK = 128: stride the write (R3 bug class).
    for (int t = tid; t < NK * NQ; t += BLOCK) {
        float r = 0.f;
#pragma unroll
        for (int j = 0; j < 8; ++j) r += red_s[t * 8 + j];
        part[blk * (NK * NQ) + t] = r;
    }
}

// ---------------- Kernel 2: sum partials, masked log-sum over q, FC ----------------
__global__ void knrm_final(const float* __restrict__ part,
                           const int*   __restrict__ qtoks,
                           const float* __restrict__ fc_w,
                           const float* __restrict__ fc_b,
                           float*       __restrict__ out) {
    __shared__ float red[NK * NQ];
    __shared__ float ks[NK];
    int b = blockIdx.x;
    int t = threadIdx.x;
    if (t < NK * NQ) {
        int q = t & 15;
        float r = 0.f;
        for (int j = 0; j < BLOCKS_PER_B; ++j)
            r += part[(b * BLOCKS_PER_B + j) * (NK * NQ) + t];
        red[t] = (qtoks[b * NQ + q] != 0) ? logf(r + 1e-6f) : 0.f;
    }
    __syncthreads();
    if (t < NK) {
        float s = 0.f;
        for (int q = 0; q < NQ; ++q) s += red[t * NQ + q];
        ks[t] = s * fc_w[t];
    }
    __syncthreads();
    if (t == 0) {
        float s = fc_b[0];
        for (int k = 0; k < NK; ++k) s += ks[k];
        out[b] = s;
    }
}

extern "C" void kernel_launch(void* const* d_in, const int* in_sizes, int n_in,
                              void* d_out, int out_size, void* d_ws, size_t ws_size,
                              hipStream_t stream) {
    const int*   doctoks   = (const int*)  d_in[0];   // [128,1024]
    const int*   querytoks = (const int*)  d_in[1];   // [128,16]
    // d_in[2] = query_idf: unused by the reference
    const float* emb       = (const float*)d_in[3];   // [100000,300]
    const float* mus       = (const float*)d_in[4];   // [11]
    const float* sigmas    = (const float*)d_in[5];   // [11]
    const float* fc_w      = (const float*)d_in[6];   // [1,11]
    const float* fc_b      = (const float*)d_in[7];   // [1]
    float* out = (float*)d_out;                        // [128]

    float* part = (float*)d_ws;                        // [512][176] floats

    knrm_main<<<NB * BLOCKS_PER_B, BLOCK, 0, stream>>>(doctoks, querytoks, emb,
                                                       mus, sigmas, part);
    knrm_final<<<NB, 192, 0, stream>>>(part, querytoks, fc_w, fc_b, out);
}